// Round 20
// baseline (71.529 us; speedup 1.0000x reference)
//
#include <hip/hip_runtime.h>

#define H_TOKN 57
#define OUT_HW 800
#define NMASK 64
#define C_IN 768
#define C8N 96
#define L_OUT 21
#define NPIX 3249          // 57*57
#define M_TOT 6498         // 2*3249
#define YSTR 24            // y57 global channel stride
#define SCALE (57.0f/800.0f)

// fused conv: BM=16, 384 threads (6 waves, 1 n-tile each) -> 407 blocks
#define BM 16
#define NTHR 384
#define ESTR 40            // bf16 LDS row stride
#define HSTR 97            // f32 LDS row stride

// binsum (MFMA one-hot segment sum)
#define TILE_H 25
#define TILE_W 100
#define ROWS_T 4
#define COLS_T 10
#define NTAPS 40
#define YTSTR 28
#define IPAD 264
#define ZPAD 264           // even: ZPAD/2 = 132 u32 per row
#define ZROWS 32
#define NSLICE 256
#define PSTR 28

// final
#define RCSTR 28
#define MFSTR 28
#define FROWS 8

static __device__ __forceinline__ unsigned short f2bf(float f) {
  unsigned u = __float_as_uint(f);
  u += 0x7FFFu + ((u >> 16) & 1u);   // RTNE
  return (unsigned short)(u >> 16);
}

using bf16x8 = __attribute__((ext_vector_type(8))) short;
using f32x4  = __attribute__((ext_vector_type(4))) float;

static __device__ __forceinline__ ushort4 cvt4(float4 v) {
  ushort4 s; s.x = f2bf(v.x); s.y = f2bf(v.y); s.z = f2bf(v.z); s.w = f2bf(v.w);
  return s;
}

// ---------- Kernel A (fused): conv1(MFMA bf16, dbuf) + relu + conv2 -> y57 ----------
__global__ __launch_bounds__(NTHR) void fused_conv_kernel(
    const float* __restrict__ e, const float* __restrict__ w1,
    const float* __restrict__ b1, const float* __restrict__ w2,
    float* __restrict__ y57)
{
  __shared__ __align__(16) unsigned short eA[2][BM * ESTR];
  __shared__ __align__(16) unsigned short wB[2][C8N * ESTR];
  __shared__ __align__(16) float h_lds[BM * HSTR];
  __shared__ float w2_lds[L_OUT * C8N];
  __shared__ float b1_lds[C8N];

  const int tid = threadIdx.x;
  const int m0 = blockIdx.x * BM;
  const int lane = tid & 63;
  const int wv = tid >> 6;            // 0..5 = n-tile
  const int l15 = lane & 15;
  const int khi = (lane >> 4) << 3;

  for (int i = tid; i < L_OUT * C8N; i += NTHR) w2_lds[i] = w2[i];
  if (tid < C8N) b1_lds[tid] = b1[tid];

  const bool estage = tid < 128;
  const int er = tid >> 3, ec4 = (tid & 7) << 2;
  int ep = m0 + er; if (ep >= M_TOT) ep = M_TOT - 1;
  const float* eptr = e + (size_t)ep * C_IN + ec4;
  const int f0 = tid, f1 = tid + NTHR;
  const int wr0 = f0 >> 3, wc40 = (f0 & 7) << 2;
  const int wr1 = f1 >> 3, wc41 = (f1 & 7) << 2;
  const float* wptr0 = w1 + (size_t)wr0 * C_IN + wc40;
  const float* wptr1 = w1 + (size_t)wr1 * C_IN + wc41;

  f32x4 acc = {0.f, 0.f, 0.f, 0.f};

  float4 eReg = estage ? *(const float4*)(eptr) : make_float4(0,0,0,0);
  float4 wReg0 = *(const float4*)(wptr0);
  float4 wReg1 = *(const float4*)(wptr1);

  int cur = 0;
  for (int k0 = 0; k0 < C_IN; k0 += 32, cur ^= 1) {
    if (estage) *(ushort4*)&eA[cur][er * ESTR + ec4] = cvt4(eReg);
    *(ushort4*)&wB[cur][wr0 * ESTR + wc40] = cvt4(wReg0);
    *(ushort4*)&wB[cur][wr1 * ESTR + wc41] = cvt4(wReg1);
    if (k0 + 32 < C_IN) {
      if (estage) eReg = *(const float4*)(eptr + k0 + 32);
      wReg0 = *(const float4*)(wptr0 + k0 + 32);
      wReg1 = *(const float4*)(wptr1 + k0 + 32);
    }
    __syncthreads();
    bf16x8 a = *(bf16x8*)&eA[cur][l15 * ESTR + khi];
    bf16x8 b = *(bf16x8*)&wB[cur][(wv * 16 + l15) * ESTR + khi];
    acc = __builtin_amdgcn_mfma_f32_16x16x32_bf16(a, b, acc, 0, 0, 0);
  }
  __syncthreads();
  {
    int n = wv * 16 + l15;
    float bv = b1_lds[n];
    #pragma unroll
    for (int r = 0; r < 4; ++r) {
      int pl = ((lane >> 4) << 2) + r;
      h_lds[pl * HSTR + n] = fmaxf(acc[r] + bv, 0.f);
    }
  }
  __syncthreads();
  {
    int px = tid & (BM - 1), l = tid >> 4;
    float s = 0.f;
    if (l < L_OUT) {
      const float* hr = &h_lds[px * HSTR];
      const float* wr = &w2_lds[l * C8N];
      #pragma unroll 8
      for (int c = 0; c < C8N; ++c) s += hr[c] * wr[c];
    }
    int pp = m0 + px;
    if (pp < M_TOT) y57[(size_t)pp * YSTR + l] = s;
  }
}

// ---------- Kernel B: MFMA one-hot segment sum, pixel-paired packed writes ----------
// Thread t (<125, waves 0-1) owns a 20-px same-row run; per chunk it handles 2
// adjacent pixels at K-columns 2t,2t+1. zT writes are 12 packed u32/chunk
// (2 bf16/word) instead of 24 scalar b16 -> write wave-ops per chunk 104 -> 32.
__global__ __launch_bounds__(256) void binsum_kernel(
    const int* __restrict__ labels, const float* __restrict__ y57,
    float* __restrict__ part)
{
  __shared__ __align__(16) unsigned short It[NMASK * IPAD];
  __shared__ __align__(16) unsigned short zT[ZROWS * ZPAD];
  __shared__ __align__(16) float ytile[NTAPS * YTSTR];
  const int tid = threadIdx.x;
  const int lane = tid & 63, wv = tid >> 6;
  const int l15 = lane & 15, khi = (lane >> 4) << 3;
  const int wc0 = blockIdx.x * TILE_W;
  const int hr0 = blockIdx.y * TILE_H;
  const int b = blockIdx.z;

  for (int i = tid; i < NMASK * IPAD / 2; i += 256) ((unsigned*)It)[i] = 0u;
  for (int i = tid; i < ZROWS * ZPAD / 2; i += 256) ((unsigned*)zT)[i] = 0u;

  float thb = fminf(fmaxf((hr0 + 0.5f) * SCALE - 0.5f, 0.f), 56.f);
  const int ib = min((int)thb, 55);
  float twb = fminf(fmaxf((wc0 + 0.5f) * SCALE - 0.5f, 0.f), 56.f);
  const int jb = min((int)twb, 55);

  const float* yb = y57 + (size_t)b * NPIX * YSTR;
  for (int i = tid; i < NTAPS * 6; i += 256) {
    int t = i / 6, q = (i - t * 6) * 4;
    int r = t / COLS_T, cc = t - r * COLS_T;
    int I = min(ib + r, 56), J = min(jb + cc, 56);
    *(float4*)&ytile[t * YTSTR + q] =
        *(const float4*)(yb + ((size_t)I * H_TOKN + J) * YSTR + q);
  }

  // pixel-pair mapping: t<125 owns row dh=t/5, 20-px run base (t%5)*20;
  // per chunk c it does pixels (base+2c, base+2c+1) at K-cols (2t, 2t+1).
  const bool valid = tid < 125;
  const int dh = tid / 5;
  const int dwb = (tid - dh * 5) * 20;
  const int hh = hr0 + dh;
  float th = fminf(fmaxf((hh + 0.5f) * SCALE - 0.5f, 0.f), 56.f);
  int i0 = min((int)th, 55);
  const float fh = th - (float)i0;
  const int ri = i0 - ib;
  const int* lrow = labels + ((size_t)b * OUT_HW + hh) * OUT_HW;

  f32x4 acc0 = {0.f,0.f,0.f,0.f}, acc1 = {0.f,0.f,0.f,0.f};
  int prevm0 = 0, prevm1 = 0;
  const unsigned short one = 0x3F80;

  float u0[24], u1[24];
  int curj = -1000;
  #define LOADU(U, rj) { \
    const float* ta = &ytile[(ri * COLS_T + (rj)) * YTSTR]; \
    const float* tc = ta + COLS_T * YTSTR; \
    _Pragma("unroll") \
    for (int q = 0; q < 6; ++q) { \
      float4 A = *(const float4*)(ta + 4 * q); \
      float4 C = *(const float4*)(tc + 4 * q); \
      U[4*q+0] = A.x + fh * (C.x - A.x); \
      U[4*q+1] = A.y + fh * (C.y - A.y); \
      U[4*q+2] = A.z + fh * (C.z - A.z); \
      U[4*q+3] = A.w + fh * (C.w - A.w); } }

  __syncthreads();
  if (valid) ((unsigned*)zT)[24 * (ZPAD/2) + tid] = 0x3F803F80u;  // ones -> cnt

  for (int c = 0; c < 10; ++c) {
    if (valid) {
      int ww0 = wc0 + dwb + 2 * c;
      int2 la = *(const int2*)(lrow + ww0);
      // pixel 0
      float tw0 = fminf(fmaxf((ww0 + 0.5f) * SCALE - 0.5f, 0.f), 56.f);
      int j00 = min((int)tw0, 55);
      float fw0 = tw0 - (float)j00;
      int rj0 = j00 - jb;
      // pixel 1
      float tw1 = fminf(fmaxf((ww0 + 1.5f) * SCALE - 0.5f, 0.f), 56.f);
      int j01 = min((int)tw1, 55);
      float fw1 = tw1 - (float)j01;
      int rj1 = j01 - jb;
      // tap cache covers [curj, curj+1]; pixels need rj0 and rj1 (rj1>=rj0)
      if (rj1 != curj) {
        if (rj1 == curj + 1) {
          #pragma unroll
          for (int ch = 0; ch < 24; ++ch) u0[ch] = u1[ch];
        } else {
          LOADU(u0, rj1)
        }
        LOADU(u1, rj1 + 1)
        curj = rj1;
      }
      // z for pixel1 from (u0,u1) at curj=rj1; pixel0: if rj0==rj1 same pair,
      // else rj0==rj1-1 -> need column rj0 = previously u0... handle via w-shift:
      // when rj0 < rj1, pixel0's taps are (rj0, rj0+1) = (curj-1, curj): its
      // lerp uses columns we no longer hold -> recompute pixel0 weights against
      // (u0,u1) is invalid. Instead fold: z0 = lerp(col rj0, col rj0+1, fw0).
      // col rj0+1 == u0 (curj). col rj0 would be lost; but fw0 in this case is
      // ~1 (j0 boundary) -- exact handling: load the needed pair explicitly.
      float z0[24];
      if (rj0 == curj) {
        #pragma unroll
        for (int ch = 0; ch < 24; ++ch) z0[ch] = u0[ch] + fw0 * (u1[ch] - u0[ch]);
      } else {
        // rj0 == curj-1: taps (curj-1, curj): column curj is u0.
        float um[24];
        LOADU(um, rj0)
        #pragma unroll
        for (int ch = 0; ch < 24; ++ch) z0[ch] = um[ch] + fw0 * (u0[ch] - um[ch]);
      }
      unsigned* zrow = (unsigned*)zT;
      #pragma unroll
      for (int ch = 0; ch < 24; ++ch) {
        float z1 = u0[ch] + fw1 * (u1[ch] - u0[ch]);
        zrow[ch * (ZPAD/2) + tid] =
            (unsigned)f2bf(z0[ch]) | ((unsigned)f2bf(z1) << 16);
      }
      int m0x = la.x & (NMASK - 1);
      int m1x = la.y & (NMASK - 1);
      It[prevm0 * IPAD + 2 * tid] = 0;
      It[prevm1 * IPAD + 2 * tid + 1] = 0;
      It[m0x * IPAD + 2 * tid] = one;
      It[m1x * IPAD + 2 * tid + 1] = one;
      prevm0 = m0x; prevm1 = m1x;
    }
    __syncthreads();
    #pragma unroll
    for (int ks = 0; ks < 8; ++ks) {
      bf16x8 a  = *(bf16x8*)&It[(wv * 16 + l15) * IPAD + ks * 32 + khi];
      bf16x8 b0 = *(bf16x8*)&zT[l15 * ZPAD + ks * 32 + khi];
      bf16x8 b1 = *(bf16x8*)&zT[(16 + l15) * ZPAD + ks * 32 + khi];
      acc0 = __builtin_amdgcn_mfma_f32_16x16x32_bf16(a, b0, acc0, 0, 0, 0);
      acc1 = __builtin_amdgcn_mfma_f32_16x16x32_bf16(a, b1, acc1, 0, 0, 0);
    }
    __syncthreads();
  }
  #undef LOADU

  float* pb = part + ((size_t)b * NSLICE +
                      (size_t)(blockIdx.y * gridDim.x + blockIdx.x)) * (NMASK * PSTR);
  const int g4 = (lane >> 4) << 2;
  #pragma unroll
  for (int r = 0; r < 4; ++r) {
    int m = wv * 16 + g4 + r;
    pb[m * PSTR + l15] = acc0[r];
    if (l15 <= 8) pb[m * PSTR + 16 + l15] = acc1[r];
  }
}

// ---------- Kernel B2: meanFg[b][m][28] = sum(part)/cnt + b2 (pads 0) ----------
__global__ __launch_bounds__(256) void reduce_kernel(
    const float* __restrict__ part, const float* __restrict__ b2,
    float* __restrict__ meanFg)
{
  const int bm = blockIdx.x;          // b*64 + m
  const int b = bm >> 6, m = bm & 63;
  const int tid = threadIdx.x;        // = slice
  const float* p = part + ((size_t)b * NSLICE + tid) * (NMASK * PSTR) + (size_t)m * PSTR;
  float4 v[7];
  #pragma unroll
  for (int q = 0; q < 7; ++q) v[q] = *(const float4*)(p + q * 4);
  #pragma unroll
  for (int off = 32; off > 0; off >>= 1) {
    #pragma unroll
    for (int q = 0; q < 7; ++q) {
      v[q].x += __shfl_down(v[q].x, off, 64);
      v[q].y += __shfl_down(v[q].y, off, 64);
      v[q].z += __shfl_down(v[q].z, off, 64);
      v[q].w += __shfl_down(v[q].w, off, 64);
    }
  }
  __shared__ float s_red[4][28];
  const int wid = tid >> 6, lane = tid & 63;
  if (lane == 0) {
    #pragma unroll
    for (int q = 0; q < 7; ++q) *(float4*)&s_red[wid][q * 4] = v[q];
  }
  __syncthreads();
  if (tid < 28) {
    float cnt = s_red[0][24] + s_red[1][24] + s_red[2][24] + s_red[3][24];
    float t = s_red[0][tid] + s_red[1][tid] + s_red[2][tid] + s_red[3][tid];
    float out = (tid < L_OUT) ? t / fmaxf(cnt, 1.f) + b2[tid] : 0.f;
    meanFg[(size_t)bm * MFSTR + tid] = out;
  }
}

// ---------- Kernel C: out[b][l][hh][w] = lerp_w(rowC)[l] + meanF[label][l] ----------
__global__ __launch_bounds__(256) void final_kernel(
    const float* __restrict__ y57, const int* __restrict__ labels,
    const float* __restrict__ meanFg, float* __restrict__ out)
{
  __shared__ __align__(16) float rowC[FROWS][H_TOKN * RCSTR];
  __shared__ __align__(16) float meanF[NMASK * MFSTR];
  const int tid = threadIdx.x;
  const int hh0 = blockIdx.y * FROWS;
  const int b = blockIdx.z;
  const float* yb = y57 + (size_t)b * NPIX * YSTR;

  for (int i = tid; i < FROWS * H_TOKN * 6; i += 256) {
    int r = i / (H_TOKN * 6);
    int rest = i - r * (H_TOKN * 6);
    int rr = rest / 6, q = (rest - rr * 6) * 4;
    float th = fminf(fmaxf((hh0 + r + 0.5f) * SCALE - 0.5f, 0.f), 56.f);
    int i0 = min((int)th, 55);
    float fh = th - (float)i0;
    const float* s0 = yb + ((size_t)i0 * H_TOKN + rr) * YSTR + q;
    float4 A = *(const float4*)s0;
    float4 B = *(const float4*)(s0 + H_TOKN * YSTR);
    *(float4*)&rowC[r][rr * RCSTR + q] = make_float4(
        A.x + fh * (B.x - A.x), A.y + fh * (B.y - A.y),
        A.z + fh * (B.z - A.z), A.w + fh * (B.w - A.w));
  }
  {
    const float* src = meanFg + (size_t)b * NMASK * MFSTR;
    for (int i = tid; i < NMASK * MFSTR / 4; i += 256)
      *(float4*)&meanF[i * 4] = *(const float4*)(src + i * 4);
  }
  __syncthreads();

  for (int g = tid; g < FROWS * 200; g += 256) {
    const int row = g / 200;
    const int gg = g - row * 200;
    const int w0 = gg * 4;
    const int hh = hh0 + row;
    const int* lrow = labels + ((size_t)b * OUT_HW + hh) * OUT_HW;
    int4 la = *(const int4*)(lrow + w0);
    float* ob = out + (size_t)b * L_OUT * OUT_HW * OUT_HW + (size_t)hh * OUT_HW + w0;
    const float* rc = rowC[row];

    float fwv[4]; const float* c0p[4]; const float* mfp[4];
    {
      int lam[4] = {la.x & 63, la.y & 63, la.z & 63, la.w & 63};
      #pragma unroll
      for (int k = 0; k < 4; ++k) {
        float tw = fminf(fmaxf((w0 + k + 0.5f) * SCALE - 0.5f, 0.f), 56.f);
        int j0 = min((int)tw, 55);
        fwv[k] = tw - (float)j0;
        c0p[k] = &rc[j0 * RCSTR];
        mfp[k] = &meanF[lam[k] * MFSTR];
      }
    }
    #pragma unroll
    for (int q = 0; q < 6; ++q) {
      float4 V[4];
      #pragma unroll
      for (int k = 0; k < 4; ++k) {
        float4 A  = *(const float4*)(c0p[k] + 4 * q);
        float4 Bv = *(const float4*)(c0p[k] + RCSTR + 4 * q);
        float4 Mv = *(const float4*)(mfp[k] + 4 * q);
        V[k].x = A.x + fwv[k] * (Bv.x - A.x) + Mv.x;
        V[k].y = A.y + fwv[k] * (Bv.y - A.y) + Mv.y;
        V[k].z = A.z + fwv[k] * (Bv.z - A.z) + Mv.z;
        V[k].w = A.w + fwv[k] * (Bv.w - A.w) + Mv.w;
      }
      const int l = 4 * q;
      *(float4*)(ob + (size_t)l * 640000) = make_float4(V[0].x, V[1].x, V[2].x, V[3].x);
      if (l + 1 < L_OUT)
        *(float4*)(ob + (size_t)(l+1) * 640000) = make_float4(V[0].y, V[1].y, V[2].y, V[3].y);
      if (l + 2 < L_OUT)
        *(float4*)(ob + (size_t)(l+2) * 640000) = make_float4(V[0].z, V[1].z, V[2].z, V[3].z);
      if (l + 3 < L_OUT)
        *(float4*)(ob + (size_t)(l+3) * 640000) = make_float4(V[0].w, V[1].w, V[2].w, V[3].w);
    }
  }
}

extern "C" void kernel_launch(void* const* d_in, const int* in_sizes, int n_in,
                              void* d_out, int out_size, void* d_ws, size_t ws_size,
                              hipStream_t stream)
{
  const float* e   = (const float*)d_in[0];
  const int*   lab = (const int*)d_in[1];
  const float* w1  = (const float*)d_in[2];
  const float* b1  = (const float*)d_in[3];
  const float* w2  = (const float*)d_in[4];
  const float* b2  = (const float*)d_in[5];
  float* out = (float*)d_out;
  float* ws  = (float*)d_ws;

  float* y57_ws = ws;                                     // 6498*24 f32
  float* part   = y57_ws + (size_t)M_TOT * YSTR;          // 2*256*64*28 f32
  float* meanFg = part + (size_t)2 * NSLICE * NMASK * PSTR; // 2*64*28 f32

  fused_conv_kernel<<<dim3((M_TOT + BM - 1) / BM), NTHR, 0, stream>>>(
      e, w1, b1, w2, y57_ws);
  binsum_kernel<<<dim3(OUT_HW / TILE_W, OUT_HW / TILE_H, 2), 256, 0, stream>>>(
      lab, y57_ws, part);
  reduce_kernel<<<dim3(2 * NMASK), 256, 0, stream>>>(part, b2, meanFg);
  final_kernel<<<dim3(1, OUT_HW / FROWS, 2), 256, 0, stream>>>(
      y57_ws, lab, meanFg, out);
}

// Round 21
// 64.030 us; speedup vs baseline: 1.1171x; 1.1171x over previous
//
#include <hip/hip_runtime.h>

#define H_TOKN 57
#define OUT_HW 800
#define NMASK 64
#define C_IN 768
#define C8N 96
#define L_OUT 21
#define NPIX 3249          // 57*57
#define M_TOT 6498         // 2*3249
#define YSTR 24            // y57 global channel stride
#define SCALE (57.0f/800.0f)

// fused conv: BM=16, 384 threads (6 waves), K-tile 64 -> 12 barriers
#define BM 16
#define NTHR 384
#define ESTR 72            // bf16 LDS row stride for K=64 tile
#define HSTR 97            // f32 LDS row stride

// binsum (MFMA one-hot segment sum)
#define TILE_H 25
#define TILE_W 100
#define ROWS_T 4
#define COLS_T 10
#define NTAPS 40
#define YTSTR 28
#define IPAD 264
#define ZPAD 264
#define ZROWS 32
#define NSLICE 256
#define PSTR 28

// final
#define RCSTR 28
#define MFSTR 28
#define FROWS 8

static __device__ __forceinline__ unsigned short f2bf(float f) {
  unsigned u = __float_as_uint(f);
  u += 0x7FFFu + ((u >> 16) & 1u);   // RTNE
  return (unsigned short)(u >> 16);
}

using bf16x8 = __attribute__((ext_vector_type(8))) short;
using f32x4  = __attribute__((ext_vector_type(4))) float;

static __device__ __forceinline__ ushort4 cvt4(float4 v) {
  ushort4 s; s.x = f2bf(v.x); s.y = f2bf(v.y); s.z = f2bf(v.z); s.w = f2bf(v.w);
  return s;
}

// ---------- Kernel A (fused): conv1(MFMA bf16, K=64 dbuf) + relu + conv2 ----------
// 407 blocks, 6 waves (1 n-tile each). 12 K-iterations, one barrier each; the
// prefetch for iter k+1 has {barrier + 2 MFMA phases} to land.
__global__ __launch_bounds__(NTHR) void fused_conv_kernel(
    const float* __restrict__ e, const float* __restrict__ w1,
    const float* __restrict__ b1, const float* __restrict__ w2,
    float* __restrict__ y57)
{
  __shared__ __align__(16) unsigned short eA[2][BM * ESTR];   // 2x2.3KB
  __shared__ __align__(16) unsigned short wB[2][C8N * ESTR];  // 2x13.8KB
  __shared__ __align__(16) float h_lds[BM * HSTR];            // 6.2KB
  __shared__ float w2_lds[L_OUT * C8N];
  __shared__ float b1_lds[C8N];

  const int tid = threadIdx.x;
  const int m0 = blockIdx.x * BM;
  const int lane = tid & 63;
  const int wv = tid >> 6;            // 0..5 = n-tile
  const int l15 = lane & 15;
  const int khi = (lane >> 4) << 3;   // 0,8,16,24 within each 32-chunk

  for (int i = tid; i < L_OUT * C8N; i += NTHR) w2_lds[i] = w2[i];
  if (tid < C8N) b1_lds[tid] = b1[tid];

  // staging: e tile 16 rows x 16 f4 by threads 0..255 (1 f4 each);
  //          w1 tile 96 rows x 16 f4 by all 384 threads (4 f4 each)
  const bool estage = tid < 256;
  const int er = tid >> 4, ec4 = (tid & 15) << 2;
  int ep = m0 + er; if (ep >= M_TOT) ep = M_TOT - 1;
  const float* eptr = e + (size_t)ep * C_IN + ec4;
  int wr_[4], wc4_[4];
  const float* wptr[4];
  #pragma unroll
  for (int q = 0; q < 4; ++q) {
    int f = tid + q * NTHR;
    wr_[q] = f >> 4; wc4_[q] = (f & 15) << 2;
    wptr[q] = w1 + (size_t)wr_[q] * C_IN + wc4_[q];
  }

  f32x4 acc = {0.f, 0.f, 0.f, 0.f};

  float4 eReg = estage ? *(const float4*)(eptr) : make_float4(0,0,0,0);
  float4 wReg[4];
  #pragma unroll
  for (int q = 0; q < 4; ++q) wReg[q] = *(const float4*)(wptr[q]);

  int cur = 0;
  for (int k0 = 0; k0 < C_IN; k0 += 64, cur ^= 1) {
    if (estage) *(ushort4*)&eA[cur][er * ESTR + ec4] = cvt4(eReg);
    #pragma unroll
    for (int q = 0; q < 4; ++q)
      *(ushort4*)&wB[cur][wr_[q] * ESTR + wc4_[q]] = cvt4(wReg[q]);
    if (k0 + 64 < C_IN) {
      if (estage) eReg = *(const float4*)(eptr + k0 + 64);
      #pragma unroll
      for (int q = 0; q < 4; ++q) wReg[q] = *(const float4*)(wptr[q] + k0 + 64);
    }
    __syncthreads();
    bf16x8 a0 = *(bf16x8*)&eA[cur][l15 * ESTR + khi];
    bf16x8 b0 = *(bf16x8*)&wB[cur][(wv * 16 + l15) * ESTR + khi];
    acc = __builtin_amdgcn_mfma_f32_16x16x32_bf16(a0, b0, acc, 0, 0, 0);
    bf16x8 a1 = *(bf16x8*)&eA[cur][l15 * ESTR + 32 + khi];
    bf16x8 b1v = *(bf16x8*)&wB[cur][(wv * 16 + l15) * ESTR + 32 + khi];
    acc = __builtin_amdgcn_mfma_f32_16x16x32_bf16(a1, b1v, acc, 0, 0, 0);
  }
  __syncthreads();
  // h = relu(acc + b1).  D: col=lane&15 (=n within tile), row=4*(lane>>4)+reg (=px)
  {
    int n = wv * 16 + l15;
    float bv = b1_lds[n];
    #pragma unroll
    for (int r = 0; r < 4; ++r) {
      int pl = ((lane >> 4) << 2) + r;
      h_lds[pl * HSTR + n] = fmaxf(acc[r] + bv, 0.f);
    }
  }
  __syncthreads();
  // conv2: one output per thread (384 = 16 px x 24 l)
  {
    int px = tid & (BM - 1), l = tid >> 4;
    float s = 0.f;
    if (l < L_OUT) {
      const float* hr = &h_lds[px * HSTR];
      const float* wr = &w2_lds[l * C8N];
      #pragma unroll 8
      for (int c = 0; c < C8N; ++c) s += hr[c] * wr[c];
    }
    int pp = m0 + px;
    if (pp < M_TOT) y57[(size_t)pp * YSTR + l] = s;
  }
}

// ---------- Kernel B: MFMA one-hot segment sum, register tap-caching ----------
__global__ __launch_bounds__(256) void binsum_kernel(
    const int* __restrict__ labels, const float* __restrict__ y57,
    float* __restrict__ part)
{
  __shared__ __align__(16) unsigned short It[NMASK * IPAD];
  __shared__ __align__(16) unsigned short zT[ZROWS * ZPAD];
  __shared__ __align__(16) float ytile[NTAPS * YTSTR];
  const int tid = threadIdx.x;
  const int lane = tid & 63, wv = tid >> 6;
  const int l15 = lane & 15, khi = (lane >> 4) << 3;
  const int wc0 = blockIdx.x * TILE_W;
  const int hr0 = blockIdx.y * TILE_H;
  const int b = blockIdx.z;

  for (int i = tid; i < NMASK * IPAD / 2; i += 256) ((unsigned*)It)[i] = 0u;
  for (int i = tid; i < ZROWS * ZPAD / 2; i += 256) ((unsigned*)zT)[i] = 0u;

  float thb = fminf(fmaxf((hr0 + 0.5f) * SCALE - 0.5f, 0.f), 56.f);
  const int ib = min((int)thb, 55);
  float twb = fminf(fmaxf((wc0 + 0.5f) * SCALE - 0.5f, 0.f), 56.f);
  const int jb = min((int)twb, 55);

  const float* yb = y57 + (size_t)b * NPIX * YSTR;
  for (int i = tid; i < NTAPS * 6; i += 256) {
    int t = i / 6, q = (i - t * 6) * 4;
    int r = t / COLS_T, cc = t - r * COLS_T;
    int I = min(ib + r, 56), J = min(jb + cc, 56);
    *(float4*)&ytile[t * YTSTR + q] =
        *(const float4*)(yb + ((size_t)I * H_TOKN + J) * YSTR + q);
  }

  const bool valid = tid < 250;
  const int dh = tid / 10;
  const int dwb = (tid - dh * 10) * 10;
  const int hh = hr0 + dh;
  float th = fminf(fmaxf((hh + 0.5f) * SCALE - 0.5f, 0.f), 56.f);
  int i0 = min((int)th, 55);
  const float fh = th - (float)i0;
  const int ri = i0 - ib;
  const int* lrow = labels + ((size_t)b * OUT_HW + hh) * OUT_HW;

  f32x4 acc0 = {0.f,0.f,0.f,0.f}, acc1 = {0.f,0.f,0.f,0.f};
  int prevm = 0;
  const unsigned short one = 0x3F80;

  float u0[24], u1[24];
  int curj = -1000;
  #define LOADU(U, rj) { \
    const float* ta = &ytile[(ri * COLS_T + (rj)) * YTSTR]; \
    const float* tc = ta + COLS_T * YTSTR; \
    _Pragma("unroll") \
    for (int q = 0; q < 6; ++q) { \
      float4 A = *(const float4*)(ta + 4 * q); \
      float4 C = *(const float4*)(tc + 4 * q); \
      U[4*q+0] = A.x + fh * (C.x - A.x); \
      U[4*q+1] = A.y + fh * (C.y - A.y); \
      U[4*q+2] = A.z + fh * (C.z - A.z); \
      U[4*q+3] = A.w + fh * (C.w - A.w); } }

  __syncthreads();
  if (valid) zT[24 * ZPAD + tid] = one;

  for (int c = 0; c < 10; ++c) {
    if (valid) {
      int ww = wc0 + dwb + c;
      float tw = fminf(fmaxf((ww + 0.5f) * SCALE - 0.5f, 0.f), 56.f);
      int j0 = min((int)tw, 55);
      float fw = tw - (float)j0;
      int rj = j0 - jb;
      if (rj != curj) {
        if (rj == curj + 1) {
          #pragma unroll
          for (int ch = 0; ch < 24; ++ch) u0[ch] = u1[ch];
        } else {
          LOADU(u0, rj)
        }
        LOADU(u1, rj + 1)
        curj = rj;
      }
      int m = lrow[ww] & (NMASK - 1);
      #pragma unroll
      for (int ch = 0; ch < 24; ++ch)
        zT[ch * ZPAD + tid] = f2bf(u0[ch] + fw * (u1[ch] - u0[ch]));
      It[prevm * IPAD + tid] = 0;
      It[m * IPAD + tid] = one;
      prevm = m;
    }
    __syncthreads();
    #pragma unroll
    for (int ks = 0; ks < 8; ++ks) {
      bf16x8 a  = *(bf16x8*)&It[(wv * 16 + l15) * IPAD + ks * 32 + khi];
      bf16x8 b0 = *(bf16x8*)&zT[l15 * ZPAD + ks * 32 + khi];
      bf16x8 b1 = *(bf16x8*)&zT[(16 + l15) * ZPAD + ks * 32 + khi];
      acc0 = __builtin_amdgcn_mfma_f32_16x16x32_bf16(a, b0, acc0, 0, 0, 0);
      acc1 = __builtin_amdgcn_mfma_f32_16x16x32_bf16(a, b1, acc1, 0, 0, 0);
    }
    __syncthreads();
  }
  #undef LOADU

  float* pb = part + ((size_t)b * NSLICE +
                      (size_t)(blockIdx.y * gridDim.x + blockIdx.x)) * (NMASK * PSTR);
  const int g4 = (lane >> 4) << 2;
  #pragma unroll
  for (int r = 0; r < 4; ++r) {
    int m = wv * 16 + g4 + r;
    pb[m * PSTR + l15] = acc0[r];
    if (l15 <= 8) pb[m * PSTR + 16 + l15] = acc1[r];
  }
}

// ---------- Kernel B2: meanFg[b][m][28] = sum(part)/cnt + b2 (pads 0) ----------
__global__ __launch_bounds__(256) void reduce_kernel(
    const float* __restrict__ part, const float* __restrict__ b2,
    float* __restrict__ meanFg)
{
  const int bm = blockIdx.x;          // b*64 + m
  const int b = bm >> 6, m = bm & 63;
  const int tid = threadIdx.x;        // = slice
  const float* p = part + ((size_t)b * NSLICE + tid) * (NMASK * PSTR) + (size_t)m * PSTR;
  float4 v[7];
  #pragma unroll
  for (int q = 0; q < 7; ++q) v[q] = *(const float4*)(p + q * 4);
  #pragma unroll
  for (int off = 32; off > 0; off >>= 1) {
    #pragma unroll
    for (int q = 0; q < 7; ++q) {
      v[q].x += __shfl_down(v[q].x, off, 64);
      v[q].y += __shfl_down(v[q].y, off, 64);
      v[q].z += __shfl_down(v[q].z, off, 64);
      v[q].w += __shfl_down(v[q].w, off, 64);
    }
  }
  __shared__ float s_red[4][28];
  const int wid = tid >> 6, lane = tid & 63;
  if (lane == 0) {
    #pragma unroll
    for (int q = 0; q < 7; ++q) *(float4*)&s_red[wid][q * 4] = v[q];
  }
  __syncthreads();
  if (tid < 28) {
    float cnt = s_red[0][24] + s_red[1][24] + s_red[2][24] + s_red[3][24];
    float t = s_red[0][tid] + s_red[1][tid] + s_red[2][tid] + s_red[3][tid];
    float out = (tid < L_OUT) ? t / fmaxf(cnt, 1.f) + b2[tid] : 0.f;
    meanFg[(size_t)bm * MFSTR + tid] = out;
  }
}

// ---------- Kernel C: out[b][l][hh][w] = lerp_w(rowC)[l] + meanF[label][l] ----------
__global__ __launch_bounds__(256) void final_kernel(
    const float* __restrict__ y57, const int* __restrict__ labels,
    const float* __restrict__ meanFg, float* __restrict__ out)
{
  __shared__ __align__(16) float rowC[FROWS][H_TOKN * RCSTR];
  __shared__ __align__(16) float meanF[NMASK * MFSTR];
  const int tid = threadIdx.x;
  const int hh0 = blockIdx.y * FROWS;
  const int b = blockIdx.z;
  const float* yb = y57 + (size_t)b * NPIX * YSTR;

  for (int i = tid; i < FROWS * H_TOKN * 6; i += 256) {
    int r = i / (H_TOKN * 6);
    int rest = i - r * (H_TOKN * 6);
    int rr = rest / 6, q = (rest - rr * 6) * 4;
    float th = fminf(fmaxf((hh0 + r + 0.5f) * SCALE - 0.5f, 0.f), 56.f);
    int i0 = min((int)th, 55);
    float fh = th - (float)i0;
    const float* s0 = yb + ((size_t)i0 * H_TOKN + rr) * YSTR + q;
    float4 A = *(const float4*)s0;
    float4 B = *(const float4*)(s0 + H_TOKN * YSTR);
    *(float4*)&rowC[r][rr * RCSTR + q] = make_float4(
        A.x + fh * (B.x - A.x), A.y + fh * (B.y - A.y),
        A.z + fh * (B.z - A.z), A.w + fh * (B.w - A.w));
  }
  {
    const float* src = meanFg + (size_t)b * NMASK * MFSTR;
    for (int i = tid; i < NMASK * MFSTR / 4; i += 256)
      *(float4*)&meanF[i * 4] = *(const float4*)(src + i * 4);
  }
  __syncthreads();

  for (int g = tid; g < FROWS * 200; g += 256) {
    const int row = g / 200;
    const int gg = g - row * 200;
    const int w0 = gg * 4;
    const int hh = hh0 + row;
    const int* lrow = labels + ((size_t)b * OUT_HW + hh) * OUT_HW;
    int4 la = *(const int4*)(lrow + w0);
    float* ob = out + (size_t)b * L_OUT * OUT_HW * OUT_HW + (size_t)hh * OUT_HW + w0;
    const float* rc = rowC[row];

    float fwv[4]; const float* c0p[4]; const float* mfp[4];
    {
      int lam[4] = {la.x & 63, la.y & 63, la.z & 63, la.w & 63};
      #pragma unroll
      for (int k = 0; k < 4; ++k) {
        float tw = fminf(fmaxf((w0 + k + 0.5f) * SCALE - 0.5f, 0.f), 56.f);
        int j0 = min((int)tw, 55);
        fwv[k] = tw - (float)j0;
        c0p[k] = &rc[j0 * RCSTR];
        mfp[k] = &meanF[lam[k] * MFSTR];
      }
    }
    #pragma unroll
    for (int q = 0; q < 6; ++q) {
      float4 V[4];
      #pragma unroll
      for (int k = 0; k < 4; ++k) {
        float4 A  = *(const float4*)(c0p[k] + 4 * q);
        float4 Bv = *(const float4*)(c0p[k] + RCSTR + 4 * q);
        float4 Mv = *(const float4*)(mfp[k] + 4 * q);
        V[k].x = A.x + fwv[k] * (Bv.x - A.x) + Mv.x;
        V[k].y = A.y + fwv[k] * (Bv.y - A.y) + Mv.y;
        V[k].z = A.z + fwv[k] * (Bv.z - A.z) + Mv.z;
        V[k].w = A.w + fwv[k] * (Bv.w - A.w) + Mv.w;
      }
      const int l = 4 * q;
      *(float4*)(ob + (size_t)l * 640000) = make_float4(V[0].x, V[1].x, V[2].x, V[3].x);
      if (l + 1 < L_OUT)
        *(float4*)(ob + (size_t)(l+1) * 640000) = make_float4(V[0].y, V[1].y, V[2].y, V[3].y);
      if (l + 2 < L_OUT)
        *(float4*)(ob + (size_t)(l+2) * 640000) = make_float4(V[0].z, V[1].z, V[2].z, V[3].z);
      if (l + 3 < L_OUT)
        *(float4*)(ob + (size_t)(l+3) * 640000) = make_float4(V[0].w, V[1].w, V[2].w, V[3].w);
    }
  }
}

extern "C" void kernel_launch(void* const* d_in, const int* in_sizes, int n_in,
                              void* d_out, int out_size, void* d_ws, size_t ws_size,
                              hipStream_t stream)
{
  const float* e   = (const float*)d_in[0];
  const int*   lab = (const int*)d_in[1];
  const float* w1  = (const float*)d_in[2];
  const float* b1  = (const float*)d_in[3];
  const float* w2  = (const float*)d_in[4];
  const float* b2  = (const float*)d_in[5];
  float* out = (float*)d_out;
  float* ws  = (float*)d_ws;

  float* y57_ws = ws;                                     // 6498*24 f32
  float* part   = y57_ws + (size_t)M_TOT * YSTR;          // 2*256*64*28 f32
  float* meanFg = part + (size_t)2 * NSLICE * NMASK * PSTR; // 2*64*28 f32

  fused_conv_kernel<<<dim3((M_TOT + BM - 1) / BM), NTHR, 0, stream>>>(
      e, w1, b1, w2, y57_ws);
  binsum_kernel<<<dim3(OUT_HW / TILE_W, OUT_HW / TILE_H, 2), 256, 0, stream>>>(
      lab, y57_ws, part);
  reduce_kernel<<<dim3(2 * NMASK), 256, 0, stream>>>(part, b2, meanFg);
  final_kernel<<<dim3(1, OUT_HW / FROWS, 2), 256, 0, stream>>>(
      y57_ws, lab, meanFg, out);
}

// Round 22
// 63.159 us; speedup vs baseline: 1.1325x; 1.0138x over previous
//
#include <hip/hip_runtime.h>

#define H_TOKN 57
#define OUT_HW 800
#define NMASK 64
#define C_IN 768
#define C8N 96
#define L_OUT 21
#define NPIX 3249          // 57*57
#define M_TOT 6498         // 2*3249
#define YSTR 24            // y57 global channel stride
#define SCALE (57.0f/800.0f)

// fused conv: BM=16, 384 threads (6 waves), K-tile 64, depth-2 reg prefetch
#define BM 16
#define NTHR 384
#define ESTR 72            // bf16 LDS row stride for K=64 tile
#define HSTR 97            // f32 LDS row stride
#define KTILES 12          // 768/64

// binsum (MFMA one-hot segment sum)
#define TILE_H 25
#define TILE_W 100
#define ROWS_T 4
#define COLS_T 10
#define NTAPS 40
#define YTSTR 28
#define IPAD 264
#define ZPAD 264
#define ZROWS 32
#define NSLICE 256
#define PSTR 28

// final
#define RCSTR 28
#define MFSTR 28
#define FROWS 8

static __device__ __forceinline__ unsigned short f2bf(float f) {
  unsigned u = __float_as_uint(f);
  u += 0x7FFFu + ((u >> 16) & 1u);   // RTNE
  return (unsigned short)(u >> 16);
}

using bf16x8 = __attribute__((ext_vector_type(8))) short;
using f32x4  = __attribute__((ext_vector_type(4))) float;

static __device__ __forceinline__ ushort4 cvt4(float4 v) {
  ushort4 s; s.x = f2bf(v.x); s.y = f2bf(v.y); s.z = f2bf(v.z); s.w = f2bf(v.w);
  return s;
}

// ---------- Kernel A (fused): conv1(MFMA bf16, K=64, depth-2 prefetch) ----------
// 407 blocks, 6 waves (1 n-tile each). 12 K-iterations; the load for tile t+2
// is issued at iter t -> ~2 iterations (~1500cyc) of latency cover.
__global__ __launch_bounds__(NTHR) void fused_conv_kernel(
    const float* __restrict__ e, const float* __restrict__ w1,
    const float* __restrict__ b1, const float* __restrict__ w2,
    float* __restrict__ y57)
{
  __shared__ __align__(16) unsigned short eA[2][BM * ESTR];
  __shared__ __align__(16) unsigned short wB[2][C8N * ESTR];
  __shared__ __align__(16) float h_lds[BM * HSTR];
  __shared__ float w2_lds[L_OUT * C8N];
  __shared__ float b1_lds[C8N];

  const int tid = threadIdx.x;
  const int m0 = blockIdx.x * BM;
  const int lane = tid & 63;
  const int wv = tid >> 6;            // 0..5 = n-tile
  const int l15 = lane & 15;
  const int khi = (lane >> 4) << 3;

  for (int i = tid; i < L_OUT * C8N; i += NTHR) w2_lds[i] = w2[i];
  if (tid < C8N) b1_lds[tid] = b1[tid];

  const bool estage = tid < 256;
  const int er = tid >> 4, ec4 = (tid & 15) << 2;
  int ep = m0 + er; if (ep >= M_TOT) ep = M_TOT - 1;
  const float* eptr = e + (size_t)ep * C_IN + ec4;
  int wr_[4], wc4_[4];
  const float* wptr[4];
  #pragma unroll
  for (int q = 0; q < 4; ++q) {
    int f = tid + q * NTHR;
    wr_[q] = f >> 4; wc4_[q] = (f & 15) << 2;
    wptr[q] = w1 + (size_t)wr_[q] * C_IN + wc4_[q];
  }

  f32x4 acc = {0.f, 0.f, 0.f, 0.f};

  // depth-2 prefetch: rg[0]=tile0, rg[1]=tile1
  float4 eR[2]; float4 wR[2][4];
  eR[0] = estage ? *(const float4*)(eptr) : make_float4(0,0,0,0);
  eR[1] = estage ? *(const float4*)(eptr + 64) : make_float4(0,0,0,0);
  #pragma unroll
  for (int q = 0; q < 4; ++q) {
    wR[0][q] = *(const float4*)(wptr[q]);
    wR[1][q] = *(const float4*)(wptr[q] + 64);
  }

  #pragma unroll
  for (int t = 0; t < KTILES; ++t) {
    const int cur = t & 1;
    const int k0 = t * 64;
    if (estage) *(ushort4*)&eA[cur][er * ESTR + ec4] = cvt4(eR[cur]);
    #pragma unroll
    for (int q = 0; q < 4; ++q)
      *(ushort4*)&wB[cur][wr_[q] * ESTR + wc4_[q]] = cvt4(wR[cur][q]);
    if (t + 2 < KTILES) {
      if (estage) eR[cur] = *(const float4*)(eptr + k0 + 128);
      #pragma unroll
      for (int q = 0; q < 4; ++q) wR[cur][q] = *(const float4*)(wptr[q] + k0 + 128);
    }
    __syncthreads();
    bf16x8 a0 = *(bf16x8*)&eA[cur][l15 * ESTR + khi];
    bf16x8 b0 = *(bf16x8*)&wB[cur][(wv * 16 + l15) * ESTR + khi];
    acc = __builtin_amdgcn_mfma_f32_16x16x32_bf16(a0, b0, acc, 0, 0, 0);
    bf16x8 a1 = *(bf16x8*)&eA[cur][l15 * ESTR + 32 + khi];
    bf16x8 b1v = *(bf16x8*)&wB[cur][(wv * 16 + l15) * ESTR + 32 + khi];
    acc = __builtin_amdgcn_mfma_f32_16x16x32_bf16(a1, b1v, acc, 0, 0, 0);
  }
  __syncthreads();
  {
    int n = wv * 16 + l15;
    float bv = b1_lds[n];
    #pragma unroll
    for (int r = 0; r < 4; ++r) {
      int pl = ((lane >> 4) << 2) + r;
      h_lds[pl * HSTR + n] = fmaxf(acc[r] + bv, 0.f);
    }
  }
  __syncthreads();
  {
    int px = tid & (BM - 1), l = tid >> 4;
    float s = 0.f;
    if (l < L_OUT) {
      const float* hr = &h_lds[px * HSTR];
      const float* wr = &w2_lds[l * C8N];
      #pragma unroll 8
      for (int c = 0; c < C8N; ++c) s += hr[c] * wr[c];
    }
    int pp = m0 + px;
    if (pp < M_TOT) y57[(size_t)pp * YSTR + l] = s;
  }
}

// ---------- Kernel B: MFMA one-hot segment sum; 2-wave x 4-acc MFMA phase ----------
// z-gen uses all 4 waves (250 threads); the MFMA phase runs on waves 0-1 only
// with 4 accumulators each: per ks 4 ds_read_b128 instead of 3 per wave x4
// waves -> total operand reads per chunk 96 -> 64 (LDS pipe is the bottleneck).
__global__ __launch_bounds__(256) void binsum_kernel(
    const int* __restrict__ labels, const float* __restrict__ y57,
    float* __restrict__ part)
{
  __shared__ __align__(16) unsigned short It[NMASK * IPAD];
  __shared__ __align__(16) unsigned short zT[ZROWS * ZPAD];
  __shared__ __align__(16) float ytile[NTAPS * YTSTR];
  const int tid = threadIdx.x;
  const int lane = tid & 63, wv = tid >> 6;
  const int l15 = lane & 15, khi = (lane >> 4) << 3;
  const int wc0 = blockIdx.x * TILE_W;
  const int hr0 = blockIdx.y * TILE_H;
  const int b = blockIdx.z;

  for (int i = tid; i < NMASK * IPAD / 2; i += 256) ((unsigned*)It)[i] = 0u;
  for (int i = tid; i < ZROWS * ZPAD / 2; i += 256) ((unsigned*)zT)[i] = 0u;

  float thb = fminf(fmaxf((hr0 + 0.5f) * SCALE - 0.5f, 0.f), 56.f);
  const int ib = min((int)thb, 55);
  float twb = fminf(fmaxf((wc0 + 0.5f) * SCALE - 0.5f, 0.f), 56.f);
  const int jb = min((int)twb, 55);

  const float* yb = y57 + (size_t)b * NPIX * YSTR;
  for (int i = tid; i < NTAPS * 6; i += 256) {
    int t = i / 6, q = (i - t * 6) * 4;
    int r = t / COLS_T, cc = t - r * COLS_T;
    int I = min(ib + r, 56), J = min(jb + cc, 56);
    *(float4*)&ytile[t * YTSTR + q] =
        *(const float4*)(yb + ((size_t)I * H_TOKN + J) * YSTR + q);
  }

  const bool valid = tid < 250;
  const int dh = tid / 10;
  const int dwb = (tid - dh * 10) * 10;
  const int hh = hr0 + dh;
  float th = fminf(fmaxf((hh + 0.5f) * SCALE - 0.5f, 0.f), 56.f);
  int i0 = min((int)th, 55);
  const float fh = th - (float)i0;
  const int ri = i0 - ib;
  const int* lrow = labels + ((size_t)b * OUT_HW + hh) * OUT_HW;

  f32x4 acc00 = {0.f,0.f,0.f,0.f}, acc01 = {0.f,0.f,0.f,0.f};
  f32x4 acc10 = {0.f,0.f,0.f,0.f}, acc11 = {0.f,0.f,0.f,0.f};
  int prevm = 0;
  const unsigned short one = 0x3F80;

  float u0[24], u1[24];
  int curj = -1000;
  #define LOADU(U, rj) { \
    const float* ta = &ytile[(ri * COLS_T + (rj)) * YTSTR]; \
    const float* tc = ta + COLS_T * YTSTR; \
    _Pragma("unroll") \
    for (int q = 0; q < 6; ++q) { \
      float4 A = *(const float4*)(ta + 4 * q); \
      float4 C = *(const float4*)(tc + 4 * q); \
      U[4*q+0] = A.x + fh * (C.x - A.x); \
      U[4*q+1] = A.y + fh * (C.y - A.y); \
      U[4*q+2] = A.z + fh * (C.z - A.z); \
      U[4*q+3] = A.w + fh * (C.w - A.w); } }

  __syncthreads();
  if (valid) zT[24 * ZPAD + tid] = one;

  for (int c = 0; c < 10; ++c) {
    if (valid) {
      int ww = wc0 + dwb + c;
      float tw = fminf(fmaxf((ww + 0.5f) * SCALE - 0.5f, 0.f), 56.f);
      int j0 = min((int)tw, 55);
      float fw = tw - (float)j0;
      int rj = j0 - jb;
      if (rj != curj) {
        if (rj == curj + 1) {
          #pragma unroll
          for (int ch = 0; ch < 24; ++ch) u0[ch] = u1[ch];
        } else {
          LOADU(u0, rj)
        }
        LOADU(u1, rj + 1)
        curj = rj;
      }
      int m = lrow[ww] & (NMASK - 1);
      #pragma unroll
      for (int ch = 0; ch < 24; ++ch)
        zT[ch * ZPAD + tid] = f2bf(u0[ch] + fw * (u1[ch] - u0[ch]));
      It[prevm * IPAD + tid] = 0;
      It[m * IPAD + tid] = one;
      prevm = m;
    }
    __syncthreads();
    if (wv < 2) {
      #pragma unroll
      for (int ks = 0; ks < 8; ++ks) {
        bf16x8 a0 = *(bf16x8*)&It[(wv * 32 + l15) * IPAD + ks * 32 + khi];
        bf16x8 a1 = *(bf16x8*)&It[(wv * 32 + 16 + l15) * IPAD + ks * 32 + khi];
        bf16x8 b0 = *(bf16x8*)&zT[l15 * ZPAD + ks * 32 + khi];
        bf16x8 b1 = *(bf16x8*)&zT[(16 + l15) * ZPAD + ks * 32 + khi];
        acc00 = __builtin_amdgcn_mfma_f32_16x16x32_bf16(a0, b0, acc00, 0, 0, 0);
        acc01 = __builtin_amdgcn_mfma_f32_16x16x32_bf16(a0, b1, acc01, 0, 0, 0);
        acc10 = __builtin_amdgcn_mfma_f32_16x16x32_bf16(a1, b0, acc10, 0, 0, 0);
        acc11 = __builtin_amdgcn_mfma_f32_16x16x32_bf16(a1, b1, acc11, 0, 0, 0);
      }
    }
    __syncthreads();
  }
  #undef LOADU

  if (wv < 2) {
    float* pb = part + ((size_t)b * NSLICE +
                        (size_t)(blockIdx.y * gridDim.x + blockIdx.x)) * (NMASK * PSTR);
    const int g4 = (lane >> 4) << 2;
    #pragma unroll
    for (int r = 0; r < 4; ++r) {
      int mA = wv * 32 + g4 + r;
      pb[mA * PSTR + l15] = acc00[r];
      if (l15 <= 8) pb[mA * PSTR + 16 + l15] = acc01[r];
      int mB = wv * 32 + 16 + g4 + r;
      pb[mB * PSTR + l15] = acc10[r];
      if (l15 <= 8) pb[mB * PSTR + 16 + l15] = acc11[r];
    }
  }
}

// ---------- Kernel B2: meanFg[b][m][28] = sum(part)/cnt + b2 (pads 0) ----------
__global__ __launch_bounds__(256) void reduce_kernel(
    const float* __restrict__ part, const float* __restrict__ b2,
    float* __restrict__ meanFg)
{
  const int bm = blockIdx.x;          // b*64 + m
  const int b = bm >> 6, m = bm & 63;
  const int tid = threadIdx.x;        // = slice
  const float* p = part + ((size_t)b * NSLICE + tid) * (NMASK * PSTR) + (size_t)m * PSTR;
  float4 v[7];
  #pragma unroll
  for (int q = 0; q < 7; ++q) v[q] = *(const float4*)(p + q * 4);
  #pragma unroll
  for (int off = 32; off > 0; off >>= 1) {
    #pragma unroll
    for (int q = 0; q < 7; ++q) {
      v[q].x += __shfl_down(v[q].x, off, 64);
      v[q].y += __shfl_down(v[q].y, off, 64);
      v[q].z += __shfl_down(v[q].z, off, 64);
      v[q].w += __shfl_down(v[q].w, off, 64);
    }
  }
  __shared__ float s_red[4][28];
  const int wid = tid >> 6, lane = tid & 63;
  if (lane == 0) {
    #pragma unroll
    for (int q = 0; q < 7; ++q) *(float4*)&s_red[wid][q * 4] = v[q];
  }
  __syncthreads();
  if (tid < 28) {
    float cnt = s_red[0][24] + s_red[1][24] + s_red[2][24] + s_red[3][24];
    float t = s_red[0][tid] + s_red[1][tid] + s_red[2][tid] + s_red[3][tid];
    float out = (tid < L_OUT) ? t / fmaxf(cnt, 1.f) + b2[tid] : 0.f;
    meanFg[(size_t)bm * MFSTR + tid] = out;
  }
}

// ---------- Kernel C: out[b][l][hh][w] = lerp_w(rowC)[l] + meanF[label][l] ----------
__global__ __launch_bounds__(256) void final_kernel(
    const float* __restrict__ y57, const int* __restrict__ labels,
    const float* __restrict__ meanFg, float* __restrict__ out)
{
  __shared__ __align__(16) float rowC[FROWS][H_TOKN * RCSTR];
  __shared__ __align__(16) float meanF[NMASK * MFSTR];
  const int tid = threadIdx.x;
  const int hh0 = blockIdx.y * FROWS;
  const int b = blockIdx.z;
  const float* yb = y57 + (size_t)b * NPIX * YSTR;

  for (int i = tid; i < FROWS * H_TOKN * 6; i += 256) {
    int r = i / (H_TOKN * 6);
    int rest = i - r * (H_TOKN * 6);
    int rr = rest / 6, q = (rest - rr * 6) * 4;
    float th = fminf(fmaxf((hh0 + r + 0.5f) * SCALE - 0.5f, 0.f), 56.f);
    int i0 = min((int)th, 55);
    float fh = th - (float)i0;
    const float* s0 = yb + ((size_t)i0 * H_TOKN + rr) * YSTR + q;
    float4 A = *(const float4*)s0;
    float4 B = *(const float4*)(s0 + H_TOKN * YSTR);
    *(float4*)&rowC[r][rr * RCSTR + q] = make_float4(
        A.x + fh * (B.x - A.x), A.y + fh * (B.y - A.y),
        A.z + fh * (B.z - A.z), A.w + fh * (B.w - A.w));
  }
  {
    const float* src = meanFg + (size_t)b * NMASK * MFSTR;
    for (int i = tid; i < NMASK * MFSTR / 4; i += 256)
      *(float4*)&meanF[i * 4] = *(const float4*)(src + i * 4);
  }
  __syncthreads();

  for (int g = tid; g < FROWS * 200; g += 256) {
    const int row = g / 200;
    const int gg = g - row * 200;
    const int w0 = gg * 4;
    const int hh = hh0 + row;
    const int* lrow = labels + ((size_t)b * OUT_HW + hh) * OUT_HW;
    int4 la = *(const int4*)(lrow + w0);
    float* ob = out + (size_t)b * L_OUT * OUT_HW * OUT_HW + (size_t)hh * OUT_HW + w0;
    const float* rc = rowC[row];

    float fwv[4]; const float* c0p[4]; const float* mfp[4];
    {
      int lam[4] = {la.x & 63, la.y & 63, la.z & 63, la.w & 63};
      #pragma unroll
      for (int k = 0; k < 4; ++k) {
        float tw = fminf(fmaxf((w0 + k + 0.5f) * SCALE - 0.5f, 0.f), 56.f);
        int j0 = min((int)tw, 55);
        fwv[k] = tw - (float)j0;
        c0p[k] = &rc[j0 * RCSTR];
        mfp[k] = &meanF[lam[k] * MFSTR];
      }
    }
    #pragma unroll
    for (int q = 0; q < 6; ++q) {
      float4 V[4];
      #pragma unroll
      for (int k = 0; k < 4; ++k) {
        float4 A  = *(const float4*)(c0p[k] + 4 * q);
        float4 Bv = *(const float4*)(c0p[k] + RCSTR + 4 * q);
        float4 Mv = *(const float4*)(mfp[k] + 4 * q);
        V[k].x = A.x + fwv[k] * (Bv.x - A.x) + Mv.x;
        V[k].y = A.y + fwv[k] * (Bv.y - A.y) + Mv.y;
        V[k].z = A.z + fwv[k] * (Bv.z - A.z) + Mv.z;
        V[k].w = A.w + fwv[k] * (Bv.w - A.w) + Mv.w;
      }
      const int l = 4 * q;
      *(float4*)(ob + (size_t)l * 640000) = make_float4(V[0].x, V[1].x, V[2].x, V[3].x);
      if (l + 1 < L_OUT)
        *(float4*)(ob + (size_t)(l+1) * 640000) = make_float4(V[0].y, V[1].y, V[2].y, V[3].y);
      if (l + 2 < L_OUT)
        *(float4*)(ob + (size_t)(l+2) * 640000) = make_float4(V[0].z, V[1].z, V[2].z, V[3].z);
      if (l + 3 < L_OUT)
        *(float4*)(ob + (size_t)(l+3) * 640000) = make_float4(V[0].w, V[1].w, V[2].w, V[3].w);
    }
  }
}

extern "C" void kernel_launch(void* const* d_in, const int* in_sizes, int n_in,
                              void* d_out, int out_size, void* d_ws, size_t ws_size,
                              hipStream_t stream)
{
  const float* e   = (const float*)d_in[0];
  const int*   lab = (const int*)d_in[1];
  const float* w1  = (const float*)d_in[2];
  const float* b1  = (const float*)d_in[3];
  const float* w2  = (const float*)d_in[4];
  const float* b2  = (const float*)d_in[5];
  float* out = (float*)d_out;
  float* ws  = (float*)d_ws;

  float* y57_ws = ws;                                     // 6498*24 f32
  float* part   = y57_ws + (size_t)M_TOT * YSTR;          // 2*256*64*28 f32
  float* meanFg = part + (size_t)2 * NSLICE * NMASK * PSTR; // 2*64*28 f32

  fused_conv_kernel<<<dim3((M_TOT + BM - 1) / BM), NTHR, 0, stream>>>(
      e, w1, b1, w2, y57_ws);
  binsum_kernel<<<dim3(OUT_HW / TILE_W, OUT_HW / TILE_H, 2), 256, 0, stream>>>(
      lab, y57_ws, part);
  reduce_kernel<<<dim3(2 * NMASK), 256, 0, stream>>>(part, b2, meanFg);
  final_kernel<<<dim3(1, OUT_HW / FROWS, 2), 256, 0, stream>>>(
      y57_ws, lab, meanFg, out);
}